// Round 3
// baseline (383752.075 us; speedup 1.0000x reference)
//
#include <hip/hip_runtime.h>
#include <hip/hip_cooperative_groups.h>
#include <hip/hip_bf16.h>
#include <math.h>

namespace cg = cooperative_groups;

#define T_   2048
#define N_   128
#define NS_  64
#define NA_  8
#define NFC_ 128
#define NH_  128
// derived
#define DX_  192   // (NN+1)*NS
#define DP_  16    // NN*NA
#define DM_  256   // NN*NH
#define G3_  384   // 3*NFC
#define G4_  512   // 4*NH

// ---------------- bf16 transposed-row dot (weights from MEMORY) ----------------
template<int NW>
__device__ __forceinline__ float dot_bf16T(const __hip_bfloat16* __restrict__ w,
                                           const float* __restrict__ x) {
  const uint4* wv = reinterpret_cast<const uint4*>(w);
  const float4* xv = reinterpret_cast<const float4*>(x);
  float a0 = 0.f, a1 = 0.f, a2 = 0.f, a3 = 0.f;
  #pragma unroll
  for (int i = 0; i < NW; ++i) {
    uint4 u = wv[i];
    float4 x0 = xv[2 * i];
    float4 x1 = xv[2 * i + 1];
    a0 = fmaf(__uint_as_float(u.x << 16),          x0.x, a0);
    a1 = fmaf(__uint_as_float(u.x & 0xffff0000u),  x0.y, a1);
    a2 = fmaf(__uint_as_float(u.y << 16),          x0.z, a2);
    a3 = fmaf(__uint_as_float(u.y & 0xffff0000u),  x0.w, a3);
    a0 = fmaf(__uint_as_float(u.z << 16),          x1.x, a0);
    a1 = fmaf(__uint_as_float(u.z & 0xffff0000u),  x1.y, a1);
    a2 = fmaf(__uint_as_float(u.w << 16),          x1.z, a2);
    a3 = fmaf(__uint_as_float(u.w & 0xffff0000u),  x1.w, a3);
  }
  return (a0 + a1) + (a2 + a3);
}

// ---------------- bf16 dot (weights from REGISTER array, static-unrolled) ------
template<int NW>
__device__ __forceinline__ float dot_regv(const uint4* w, const float4* __restrict__ xv) {
  float a0 = 0.f, a1 = 0.f, a2 = 0.f, a3 = 0.f;
  #pragma unroll
  for (int i = 0; i < NW; ++i) {
    uint4 u = w[i];
    float4 x0 = xv[2 * i];
    float4 x1 = xv[2 * i + 1];
    a0 = fmaf(__uint_as_float(u.x << 16),          x0.x, a0);
    a1 = fmaf(__uint_as_float(u.x & 0xffff0000u),  x0.y, a1);
    a2 = fmaf(__uint_as_float(u.y << 16),          x0.z, a2);
    a3 = fmaf(__uint_as_float(u.y & 0xffff0000u),  x0.w, a3);
    a0 = fmaf(__uint_as_float(u.z << 16),          x1.x, a0);
    a1 = fmaf(__uint_as_float(u.z & 0xffff0000u),  x1.y, a1);
    a2 = fmaf(__uint_as_float(u.w << 16),          x1.z, a2);
    a3 = fmaf(__uint_as_float(u.w & 0xffff0000u),  x1.w, a3);
  }
  return (a0 + a1) + (a2 + a3);
}

struct Params {
  const float* obs; const float* fps; const float* dones; const float* states0;
  const float* b_fcx; const float* b_fcp; const float* b_fcm;
  const float* a_src; const float* a_dst;
  const float* b_lstm; const float* b_act;
  const float* W_cri; const float* b_cri;
  const int* acts; const int* nbr;
  float* out;
  float* h_buf;    // N*NH
  float* Wh_buf;   // N*G3
  float* psrc;     // N*2
  float* pdst;     // N*2
  const __hip_bfloat16* ihT;   // [N][G4][G3]
  const __hip_bfloat16* hhT;   // [N][G4][NH]
  const __hip_bfloat16* gatT;  // [G3][G3]
  const __hip_bfloat16* fcxT;  // [N][NFC][DX]
  const __hip_bfloat16* fcpT;  // [N][NFC][DP]
  const __hip_bfloat16* fcmT;  // [N][NFC][DM]
  const __hip_bfloat16* actT;  // [N][NA][NH]
};

__device__ __forceinline__ float sigm(float x) { return 1.f / (1.f + expf(-x)); }

// ---------------- prep: transpose [A][D][G] fp32 -> [A][G][D] bf16 ----------------
__global__ void transpose_to_bf16(const float* __restrict__ src, __hip_bfloat16* __restrict__ dst,
                                  int A, int D, int G) {
  size_t total = (size_t)A * D * G;
  size_t stride = (size_t)gridDim.x * blockDim.x;
  for (size_t i = (size_t)blockIdx.x * blockDim.x + threadIdx.x; i < total; i += stride) {
    size_t dg = (size_t)D * G;
    size_t a = i / dg;
    size_t r = i - a * dg;
    size_t g = r / D, d = r - g * D;
    dst[i] = __float2bfloat16(src[a * dg + d * G + g]);
  }
}

// heads for timestep th, reading raw h (sh_h). half0: actor, half1: critic.
__device__ __forceinline__ void do_heads(const Params& p, int n, int half, int tid, int th,
                                         const float* sh_h, int nb0, int nb1) {
  if (half == 0) {
    if (tid >= 384 && tid < 448) {
      int l = tid - 384, a = l >> 3, k = l & 7;
      const uint4* wv = reinterpret_cast<const uint4*>(p.actT + ((size_t)n * NA_ + a) * NH_);
      const float4* xv = reinterpret_cast<const float4*>(sh_h);
      float pp = 0.f;
      #pragma unroll
      for (int i = 0; i < 2; ++i) {
        uint4 u = wv[k * 2 + i];
        float4 x0 = xv[(k * 2 + i) * 2];
        float4 x1 = xv[(k * 2 + i) * 2 + 1];
        pp = fmaf(__uint_as_float(u.x << 16),         x0.x, pp);
        pp = fmaf(__uint_as_float(u.x & 0xffff0000u), x0.y, pp);
        pp = fmaf(__uint_as_float(u.y << 16),         x0.z, pp);
        pp = fmaf(__uint_as_float(u.y & 0xffff0000u), x0.w, pp);
        pp = fmaf(__uint_as_float(u.z << 16),         x1.x, pp);
        pp = fmaf(__uint_as_float(u.z & 0xffff0000u), x1.y, pp);
        pp = fmaf(__uint_as_float(u.w << 16),         x1.z, pp);
        pp = fmaf(__uint_as_float(u.w & 0xffff0000u), x1.w, pp);
      }
      pp += __shfl_down(pp, 4, 8);
      pp += __shfl_down(pp, 2, 8);
      pp += __shfl_down(pp, 1, 8);
      if (k == 0) p.out[((size_t)th * N_ + n) * 9 + a] = pp + p.b_act[n * NA_ + a];
    }
  } else {
    if (tid >= 448) {
      int l = tid - 448;
      const float* wc = p.W_cri + (size_t)n * 144;
      float pp = sh_h[l] * wc[l] + sh_h[64 + l] * wc[64 + l];
      for (int off = 32; off; off >>= 1) pp += __shfl_down(pp, off);
      if (l == 0) {
        pp += p.b_cri[n];
        pp += wc[NH_ + p.acts[(size_t)th * N_ + nb0]];
        pp += wc[NH_ + NA_ + p.acts[(size_t)th * N_ + nb1]];
        p.out[((size_t)th * N_ + n) * 9 + 8] = pp;
      }
    }
  }
}

// ---------------- main: 256 WGs (2 per agent), LSTM weights in registers ----------
__global__ void __launch_bounds__(512, 2) policy_scan_regs(Params p) {
  cg::grid_group grid = cg::this_grid();
  const int tid  = threadIdx.x;
  const int b    = blockIdx.x;
  const int n    = b & 127;          // agent
  const int half = b >> 7;           // 0/1; pair (b, b+128) lands on same XCD
  const int j0   = half * 64;        // this WG's hidden-unit range [j0, j0+64)
  const int nb0  = p.nbr[n * 2 + 0];
  const int nb1  = p.nbr[n * 2 + 1];

  __shared__ __align__(16) float sh_h[NH_];      // raw h_{t-1}, full
  __shared__ __align__(16) float sh_hm[NH_];     // masked h_{t-1}, full
  __shared__ __align__(16) float sh_c[64];       // own c half
  __shared__ __align__(16) float sh_xin[DX_];
  __shared__ __align__(16) float sh_pin[DP_];
  __shared__ __align__(16) float sh_min[DM_];
  __shared__ __align__(16) float sh_feat[G3_];
  __shared__ __align__(16) float sh_sgat[G3_];
  __shared__ __align__(16) float gred[384];
  __shared__ __align__(16) float red_s[192];
  __shared__ __align__(16) float red_d[192];
  __shared__ __align__(16) float partial[512];
  __shared__ __align__(16) float sh_gates[256];  // own 256 gate rows (4 x 64)

  // ---- per-thread register-resident LSTM weights ----
  // rid in [0,256): gate row; kh: which K-half. grow = global gate row.
  const int rid = tid & 255, kh = tid >> 8;
  const int q = rid >> 6, jloc = rid & 63;
  const int grow = q * 128 + j0 + jloc;
  uint4 wih4[24];   // 192 bf16 of ih row-half
  uint4 whh4[8];    // 64 bf16 of hh row-half
  {
    const uint4* ihp = reinterpret_cast<const uint4*>(p.ihT + ((size_t)n * G4_ + grow) * G3_ + kh * 192);
    #pragma unroll
    for (int i = 0; i < 24; ++i) wih4[i] = ihp[i];
    const uint4* hhp = reinterpret_cast<const uint4*>(p.hhT + ((size_t)n * G4_ + grow) * NH_ + kh * 64);
    #pragma unroll
    for (int i = 0; i < 8; ++i) whh4[i] = hhp[i];
  }

  // ---- init state ----
  if (tid < 64) {
    sh_c[tid] = p.states0[n * (2 * NH_) + NH_ + j0 + tid];
    p.h_buf[n * NH_ + j0 + tid] = p.states0[n * (2 * NH_) + j0 + tid];
  }
  __threadfence();
  grid.sync();

  for (int t = 0; t < T_; ++t) {
    const float keep  = 1.f - p.dones[(size_t)t * N_ + n];
    const float keep0 = 1.f - p.dones[(size_t)t * N_ + nb0];
    const float keep1 = 1.f - p.dones[(size_t)t * N_ + nb1];

    if (tid < NH_) sh_h[tid] = p.h_buf[n * NH_ + tid];
    if (tid < 64)  sh_c[tid] *= keep;
    __syncthreads();
    if (tid < NH_) sh_hm[tid] = sh_h[tid] * keep;

    // heads for step t-1 (threads 384+, overlapped with staging below)
    if (t > 0) do_heads(p, n, half, tid, t - 1, sh_h, nb0, nb1);

    // ---- input staging (threads < 384) ----
    if (tid < DX_) {
      int k = tid >> 6, d = tid & 63;
      int agent = (k == 0) ? n : ((k == 1) ? nb0 : nb1);
      sh_xin[tid] = p.obs[((size_t)t * N_ + agent) * NS_ + d];
    }
    if (tid >= 192 && tid < 208) {
      int u = tid - 192;
      int k = u >> 3, a = u & 7;
      int agent = (k == 0) ? nb0 : nb1;
      sh_pin[u] = p.fps[((size_t)t * N_ + agent) * NA_ + a];
    }
    if (tid >= 128 && tid < 384) {
      int v = tid - 128;
      int k = v >> 7, f = v & 127;
      int agent = (k == 0) ? nb0 : nb1;
      float kp  = (k == 0) ? keep0 : keep1;
      sh_min[v] = p.h_buf[agent * NH_ + f] * kp;
    }
    __syncthreads();

    // ---- stage-1 FCs (full feat, redundant in both halves; L2-resident weights) ----
    if (tid < NFC_) {
      const __hip_bfloat16* w = p.fcxT + ((size_t)n * NFC_ + tid) * DX_;
      float acc = p.b_fcx[n * NFC_ + tid]
                + dot_bf16T<12>(w, sh_xin)
                + dot_bf16T<12>(w + 96, sh_xin + 96);
      sh_feat[tid] = fmaxf(acc, 0.f);
    } else if (tid < 2 * NFC_) {
      int f = tid - NFC_;
      float acc = p.b_fcp[n * NFC_ + f]
                + dot_bf16T<2>(p.fcpT + ((size_t)n * NFC_ + f) * DP_, sh_pin);
      sh_feat[NFC_ + f] = fmaxf(acc, 0.f);
    } else if (tid < 3 * NFC_) {
      int f = tid - 2 * NFC_;
      const __hip_bfloat16* w = p.fcmT + ((size_t)n * NFC_ + f) * DM_;
      float acc = p.b_fcm[n * NFC_ + f]
                + dot_bf16T<16>(w, sh_min)
                + dot_bf16T<16>(w + 128, sh_min + 128);
      sh_feat[2 * NFC_ + f] = fmaxf(acc, 0.f);
    }
    __syncthreads();

    // ---- gat: this half's 192 Wh rows, 2 threads per row (K-split) ----
    if (tid < 384) {
      int kg = (tid >= 192) ? 1 : 0;
      int r  = tid - kg * 192;
      int row = half * 192 + r;
      const __hip_bfloat16* w = p.gatT + (size_t)row * G3_ + kg * 192;
      gred[tid] = dot_bf16T<12>(w, sh_feat + kg * 192)
                + dot_bf16T<12>(w + 96, sh_feat + kg * 192 + 96);
    }
    __syncthreads();
    if (tid < 192) {
      float v = gred[tid] + gred[192 + tid];
      int row = half * 192 + tid;
      p.Wh_buf[n * G3_ + row] = v;
      red_s[tid] = v * p.a_src[row];
      red_d[tid] = v * p.a_dst[row];
    }
    __syncthreads();
    if (tid < 64) {
      float s = red_s[tid] + red_s[tid + 64] + red_s[tid + 128];
      for (int off = 32; off; off >>= 1) s += __shfl_down(s, off);
      if (tid == 0) p.psrc[n * 2 + half] = s;
    } else if (tid < 128) {
      int l = tid - 64;
      float s = red_d[l] + red_d[l + 64] + red_d[l + 128];
      for (int off = 32; off; off >>= 1) s += __shfl_down(s, off);
      if (l == 0) p.pdst[n * 2 + half] = s;
    }
    __threadfence();
    grid.sync();   // #1: Wh_buf / psrc / pdst published

    // ---- GAT ring attention (redundant per thread) ----
    float src_n = p.psrc[n * 2] + p.psrc[n * 2 + 1];
    float e_l = src_n + p.pdst[nb0 * 2] + p.pdst[nb0 * 2 + 1];
    float e_s = src_n + p.pdst[n   * 2] + p.pdst[n   * 2 + 1];
    float e_r = src_n + p.pdst[nb1 * 2] + p.pdst[nb1 * 2 + 1];
    e_l = (e_l >= 0.f) ? e_l : 0.2f * e_l;
    e_s = (e_s >= 0.f) ? e_s : 0.2f * e_s;
    e_r = (e_r >= 0.f) ? e_r : 0.2f * e_r;
    float mx = fmaxf(e_l, fmaxf(e_s, e_r));
    float wl = expf(e_l - mx), wsf = expf(e_s - mx), wr = expf(e_r - mx);
    float inv = 1.f / (wl + wsf + wr);
    wl *= inv; wsf *= inv; wr *= inv;

    if (tid < G3_) {
      float v = wsf * p.Wh_buf[n * G3_ + tid]
              + wl  * p.Wh_buf[nb0 * G3_ + tid]
              + wr  * p.Wh_buf[nb1 * G3_ + tid];
      sh_sgat[tid] = (v > 0.f) ? v : expm1f(v);
    }
    __syncthreads();

    // ---- LSTM gates from REGISTER weights (all 512 threads) ----
    {
      float acc = dot_regv<24>(wih4, reinterpret_cast<const float4*>(sh_sgat + kh * 192));
      acc      += dot_regv<8>(whh4, reinterpret_cast<const float4*>(sh_hm + kh * 64));
      partial[tid] = acc;
    }
    __syncthreads();
    if (tid < 256) {
      int gq = tid >> 6, gj = tid & 63;
      sh_gates[tid] = partial[tid] + partial[tid + 256]
                    + p.b_lstm[n * G4_ + gq * 128 + j0 + gj];
    }
    __syncthreads();

    // ---- LSTM update: own 64 hidden units ----
    if (tid < 64) {
      float gi = sh_gates[tid];
      float gf = sh_gates[64 + tid];
      float gg = sh_gates[128 + tid];
      float go = sh_gates[192 + tid];
      float c_new = sigm(gf) * sh_c[tid] + sigm(gi) * tanhf(gg);
      float h_new = sigm(go) * tanhf(c_new);
      sh_c[tid] = c_new;
      p.h_buf[n * NH_ + j0 + tid] = h_new;
    }
    __threadfence();
    grid.sync();   // #2: h published for step t+1
  }

  // ---- tail: heads for t = T-1 ----
  if (tid < NH_) sh_h[tid] = p.h_buf[n * NH_ + tid];
  __syncthreads();
  do_heads(p, n, half, tid, T_ - 1, sh_h, nb0, nb1);
}

// ---------------- fallback: fp32 streaming kernel (ws too small) ----------------
struct ParamsF {
  const float* obs; const float* fps; const float* dones; const float* states0;
  const float* W_fcx; const float* b_fcx;
  const float* W_fcp; const float* b_fcp;
  const float* W_fcm; const float* b_fcm;
  const float* W_gat; const float* a_src; const float* a_dst;
  const float* W_ih;  const float* W_hh;  const float* b_lstm;
  const float* W_act; const float* b_act;
  const float* W_cri; const float* b_cri;
  const int* acts; const int* nbr;
  float* out; float* h_buf; float* Wh_buf; float* dst_buf;
};

__global__ void __launch_bounds__(512) policy_scan_f32(ParamsF p) {
  cg::grid_group grid = cg::this_grid();
  const int tid = threadIdx.x;
  const int n   = blockIdx.x;
  const int nb0 = p.nbr[n * 2 + 0];
  const int nb1 = p.nbr[n * 2 + 1];
  __shared__ float sh_h[NH_], sh_c[NH_], sh_xin[DX_], sh_pin[DP_], sh_min[DM_];
  __shared__ float sh_feat[G3_], sh_Wh[G3_], sh_sgat[G3_], sh_gates[G4_], sh_src;
  if (tid < NH_) {
    float h0 = p.states0[n * (2 * NH_) + tid];
    float c0 = p.states0[n * (2 * NH_) + NH_ + tid];
    sh_h[tid] = h0; sh_c[tid] = c0; p.h_buf[n * NH_ + tid] = h0;
  }
  __threadfence();
  grid.sync();
  for (int t = 0; t < T_; ++t) {
    const float keep  = 1.f - p.dones[(size_t)t * N_ + n];
    const float keep0 = 1.f - p.dones[(size_t)t * N_ + nb0];
    const float keep1 = 1.f - p.dones[(size_t)t * N_ + nb1];
    if (tid < NH_) { sh_h[tid] *= keep; sh_c[tid] *= keep; }
    if (tid < DX_) {
      int k = tid >> 6, d = tid & 63;
      int agent = (k == 0) ? n : ((k == 1) ? nb0 : nb1);
      sh_xin[tid] = p.obs[((size_t)t * N_ + agent) * NS_ + d];
    }
    {
      int u = tid - DX_;
      if (u >= 0 && u < DP_) {
        int k = u >> 3, a = u & 7;
        sh_pin[u] = p.fps[((size_t)t * N_ + ((k == 0) ? nb0 : nb1)) * NA_ + a];
      }
      int v = tid - (DX_ + DP_);
      if (v >= 0 && v < DM_) {
        int k = v >> 7, f = v & 127;
        sh_min[v] = p.h_buf[((k == 0) ? nb0 : nb1) * NH_ + f] * ((k == 0) ? keep0 : keep1);
      }
    }
    __syncthreads();
    if (tid < NFC_) {
      const float* w = p.W_fcx + ((size_t)n * DX_) * NFC_ + tid;
      float acc = p.b_fcx[n * NFC_ + tid];
      #pragma unroll 4
      for (int d = 0; d < DX_; ++d) acc = fmaf(sh_xin[d], w[(size_t)d * NFC_], acc);
      sh_feat[tid] = fmaxf(acc, 0.f);
    } else if (tid < 2 * NFC_) {
      int f = tid - NFC_;
      const float* w = p.W_fcp + ((size_t)n * DP_) * NFC_ + f;
      float acc = p.b_fcp[n * NFC_ + f];
      #pragma unroll
      for (int d = 0; d < DP_; ++d) acc = fmaf(sh_pin[d], w[(size_t)d * NFC_], acc);
      sh_feat[NFC_ + f] = fmaxf(acc, 0.f);
    } else if (tid < 3 * NFC_) {
      int f = tid - 2 * NFC_;
      const float* w = p.W_fcm + ((size_t)n * DM_) * NFC_ + f;
      float acc = p.b_fcm[n * NFC_ + f];
      #pragma unroll 4
      for (int d = 0; d < DM_; ++d) acc = fmaf(sh_min[d], w[(size_t)d * NFC_], acc);
      sh_feat[2 * NFC_ + f] = fmaxf(acc, 0.f);
    }
    __syncthreads();
    if (tid < G3_) {
      const float* w = p.W_gat + tid;
      float acc = 0.f;
      #pragma unroll 4
      for (int d = 0; d < G3_; ++d) acc = fmaf(sh_feat[d], w[(size_t)d * G3_], acc);
      sh_Wh[tid] = acc;
      p.Wh_buf[n * G3_ + tid] = acc;
    }
    __syncthreads();
    if (tid < 64) {
      float s = 0.f;
      for (int g = tid; g < G3_; g += 64) s += sh_Wh[g] * p.a_src[g];
      for (int off = 32; off; off >>= 1) s += __shfl_down(s, off);
      if (tid == 0) sh_src = s;
    } else if (tid < 128) {
      int l = tid - 64;
      float s = 0.f;
      for (int g = l; g < G3_; g += 64) s += sh_Wh[g] * p.a_dst[g];
      for (int off = 32; off; off >>= 1) s += __shfl_down(s, off);
      if (l == 0) p.dst_buf[n] = s;
    }
    __threadfence();
    grid.sync();
    const float src_n = sh_src;
    float e_l = src_n + p.dst_buf[nb0];
    float e_s = src_n + p.dst_buf[n];
    float e_r = src_n + p.dst_buf[nb1];
    e_l = (e_l >= 0.f) ? e_l : 0.2f * e_l;
    e_s = (e_s >= 0.f) ? e_s : 0.2f * e_s;
    e_r = (e_r >= 0.f) ? e_r : 0.2f * e_r;
    float mx = fmaxf(e_l, fmaxf(e_s, e_r));
    float wl = expf(e_l - mx), wsf = expf(e_s - mx), wr = expf(e_r - mx);
    float inv = 1.f / (wl + wsf + wr);
    wl *= inv; wsf *= inv; wr *= inv;
    if (tid < G3_) {
      float v = wsf * sh_Wh[tid] + wl * p.Wh_buf[nb0 * G3_ + tid] + wr * p.Wh_buf[nb1 * G3_ + tid];
      sh_sgat[tid] = (v > 0.f) ? v : expm1f(v);
    }
    __syncthreads();
    {
      const int g = tid;
      const float* wih = p.W_ih + ((size_t)n * G3_) * G4_ + g;
      const float* whh = p.W_hh + ((size_t)n * NH_) * G4_ + g;
      float acc = p.b_lstm[n * G4_ + g];
      #pragma unroll 4
      for (int d = 0; d < G3_; ++d) acc = fmaf(sh_sgat[d], wih[(size_t)d * G4_], acc);
      #pragma unroll 4
      for (int d = 0; d < NH_; ++d) acc = fmaf(sh_h[d], whh[(size_t)d * G4_], acc);
      sh_gates[g] = acc;
    }
    __syncthreads();
    if (tid < NH_) {
      float gi = sh_gates[tid], gf = sh_gates[NH_ + tid];
      float gg = sh_gates[2 * NH_ + tid], go = sh_gates[3 * NH_ + tid];
      float c_new = sigm(gf) * sh_c[tid] + sigm(gi) * tanhf(gg);
      float h_new = sigm(go) * tanhf(c_new);
      sh_c[tid] = c_new; sh_h[tid] = h_new;
      p.h_buf[n * NH_ + tid] = h_new;
    }
    __syncthreads();
    if (tid < NA_) {
      const float* wa = p.W_act + ((size_t)n * NH_) * NA_ + tid;
      float acc = p.b_act[n * NA_ + tid];
      #pragma unroll 4
      for (int d = 0; d < NH_; ++d) acc = fmaf(sh_h[d], wa[(size_t)d * NA_], acc);
      p.out[((size_t)t * N_ + n) * 9 + tid] = acc;
    } else if (tid == NA_) {
      const float* wc = p.W_cri + (size_t)n * 144;
      float acc = p.b_cri[n];
      #pragma unroll 4
      for (int d = 0; d < NH_; ++d) acc = fmaf(sh_h[d], wc[d], acc);
      acc += wc[NH_ + p.acts[(size_t)t * N_ + nb0]];
      acc += wc[NH_ + NA_ + p.acts[(size_t)t * N_ + nb1]];
      p.out[((size_t)t * N_ + n) * 9 + 8] = acc;
    }
    __threadfence();
    grid.sync();
  }
}

extern "C" void kernel_launch(void* const* d_in, const int* in_sizes, int n_in,
                              void* d_out, int out_size, void* d_ws, size_t ws_size,
                              hipStream_t stream) {
  const float* obs    = (const float*)d_in[0];
  const float* fps    = (const float*)d_in[1];
  const float* dones  = (const float*)d_in[2];
  const float* states0= (const float*)d_in[3];
  const float* W_fcx  = (const float*)d_in[4];
  const float* b_fcx  = (const float*)d_in[5];
  const float* W_fcp  = (const float*)d_in[6];
  const float* b_fcp  = (const float*)d_in[7];
  const float* W_fcm  = (const float*)d_in[8];
  const float* b_fcm  = (const float*)d_in[9];
  const float* W_gat  = (const float*)d_in[10];
  const float* a_src  = (const float*)d_in[11];
  const float* a_dst  = (const float*)d_in[12];
  const float* W_ih   = (const float*)d_in[13];
  const float* W_hh   = (const float*)d_in[14];
  const float* b_lstm = (const float*)d_in[15];
  const float* W_act  = (const float*)d_in[16];
  const float* b_act  = (const float*)d_in[17];
  const float* W_cri  = (const float*)d_in[18];
  const float* b_cri  = (const float*)d_in[19];
  const int*   acts   = (const int*)d_in[20];
  const int*   nbr    = (const int*)d_in[21];

  // workspace layout (all offsets multiples of 256B)
  char* ws = (char*)d_ws;
  size_t off = 0;
  float* h_buf   = (float*)(ws + off); off += (size_t)N_ * NH_ * 4;
  float* Wh_buf  = (float*)(ws + off); off += (size_t)N_ * G3_ * 4;
  float* psrc    = (float*)(ws + off); off += 1024;
  float* pdst    = (float*)(ws + off); off += 1024;
  __hip_bfloat16* ihT  = (__hip_bfloat16*)(ws + off); off += (size_t)N_ * G4_ * G3_ * 2;
  __hip_bfloat16* hhT  = (__hip_bfloat16*)(ws + off); off += (size_t)N_ * G4_ * NH_ * 2;
  __hip_bfloat16* gatT = (__hip_bfloat16*)(ws + off); off += (size_t)G3_ * G3_ * 2;
  __hip_bfloat16* fcxT = (__hip_bfloat16*)(ws + off); off += (size_t)N_ * NFC_ * DX_ * 2;
  __hip_bfloat16* fcpT = (__hip_bfloat16*)(ws + off); off += (size_t)N_ * NFC_ * DP_ * 2;
  __hip_bfloat16* fcmT = (__hip_bfloat16*)(ws + off); off += (size_t)N_ * NFC_ * DM_ * 2;
  __hip_bfloat16* actT = (__hip_bfloat16*)(ws + off); off += (size_t)N_ * NA_ * NH_ * 2;

  if (ws_size < off) {
    ParamsF p;
    p.obs = obs; p.fps = fps; p.dones = dones; p.states0 = states0;
    p.W_fcx = W_fcx; p.b_fcx = b_fcx; p.W_fcp = W_fcp; p.b_fcp = b_fcp;
    p.W_fcm = W_fcm; p.b_fcm = b_fcm; p.W_gat = W_gat; p.a_src = a_src; p.a_dst = a_dst;
    p.W_ih = W_ih; p.W_hh = W_hh; p.b_lstm = b_lstm;
    p.W_act = W_act; p.b_act = b_act; p.W_cri = W_cri; p.b_cri = b_cri;
    p.acts = acts; p.nbr = nbr; p.out = (float*)d_out;
    p.h_buf = h_buf; p.Wh_buf = Wh_buf; p.dst_buf = psrc;
    void* args[] = { &p };
    hipLaunchCooperativeKernel((const void*)policy_scan_f32, dim3(N_), dim3(512), args, 0, stream);
    return;
  }

  // prep: transpose+convert weights to bf16 [out][in]
  {
    dim3 blk(256);
    transpose_to_bf16<<<dim3(4096), blk, 0, stream>>>(W_ih,  ihT,  N_, G3_, G4_);
    transpose_to_bf16<<<dim3(2048), blk, 0, stream>>>(W_hh,  hhT,  N_, NH_, G4_);
    transpose_to_bf16<<<dim3(256),  blk, 0, stream>>>(W_gat, gatT, 1,  G3_, G3_);
    transpose_to_bf16<<<dim3(1024), blk, 0, stream>>>(W_fcx, fcxT, N_, DX_, NFC_);
    transpose_to_bf16<<<dim3(256),  blk, 0, stream>>>(W_fcp, fcpT, N_, DP_, NFC_);
    transpose_to_bf16<<<dim3(1024), blk, 0, stream>>>(W_fcm, fcmT, N_, DM_, NFC_);
    transpose_to_bf16<<<dim3(128),  blk, 0, stream>>>(W_act, actT, N_, NH_, NA_);
  }

  Params p;
  p.obs = obs; p.fps = fps; p.dones = dones; p.states0 = states0;
  p.b_fcx = b_fcx; p.b_fcp = b_fcp; p.b_fcm = b_fcm;
  p.a_src = a_src; p.a_dst = a_dst;
  p.b_lstm = b_lstm; p.b_act = b_act;
  p.W_cri = W_cri; p.b_cri = b_cri;
  p.acts = acts; p.nbr = nbr;
  p.out = (float*)d_out;
  p.h_buf = h_buf; p.Wh_buf = Wh_buf; p.psrc = psrc; p.pdst = pdst;
  p.ihT = ihT; p.hhT = hhT; p.gatT = gatT;
  p.fcxT = fcxT; p.fcpT = fcpT; p.fcmT = fcmT; p.actT = actT;

  void* args[] = { &p };
  hipLaunchCooperativeKernel((const void*)policy_scan_regs, dim3(2 * N_), dim3(512), args, 0, stream);
}

// Round 4
// 94787.048 us; speedup vs baseline: 4.0486x; 4.0486x over previous
//
#include <hip/hip_runtime.h>
#include <hip/hip_cooperative_groups.h>
#include <hip/hip_bf16.h>
#include <math.h>

namespace cg = cooperative_groups;

#define T_   2048
#define N_   128
#define NS_  64
#define NA_  8
#define NFC_ 128
#define NH_  128
// derived
#define DX_  192   // (NN+1)*NS
#define DP_  16    // NN*NA
#define DM_  256   // NN*NH
#define G3_  384   // 3*NFC
#define G4_  512   // 4*NH

// ---------------- bf16 transposed-row dot (weights from MEMORY) ----------------
template<int NW>
__device__ __forceinline__ float dot_bf16T(const __hip_bfloat16* __restrict__ w,
                                           const float* __restrict__ x) {
  const uint4* wv = reinterpret_cast<const uint4*>(w);
  const float4* xv = reinterpret_cast<const float4*>(x);
  float a0 = 0.f, a1 = 0.f, a2 = 0.f, a3 = 0.f;
  #pragma unroll
  for (int i = 0; i < NW; ++i) {
    uint4 u = wv[i];
    float4 x0 = xv[2 * i];
    float4 x1 = xv[2 * i + 1];
    a0 = fmaf(__uint_as_float(u.x << 16),          x0.x, a0);
    a1 = fmaf(__uint_as_float(u.x & 0xffff0000u),  x0.y, a1);
    a2 = fmaf(__uint_as_float(u.y << 16),          x0.z, a2);
    a3 = fmaf(__uint_as_float(u.y & 0xffff0000u),  x0.w, a3);
    a0 = fmaf(__uint_as_float(u.z << 16),          x1.x, a0);
    a1 = fmaf(__uint_as_float(u.z & 0xffff0000u),  x1.y, a1);
    a2 = fmaf(__uint_as_float(u.w << 16),          x1.z, a2);
    a3 = fmaf(__uint_as_float(u.w & 0xffff0000u),  x1.w, a3);
  }
  return (a0 + a1) + (a2 + a3);
}

__device__ __forceinline__ float sigm(float x) { return 1.f / (1.f + expf(-x)); }

// spin until *f >= want (device-scope). Final acquire-load fences the reader CU.
__device__ __forceinline__ void spin_ge(int* f, int want) {
  if (__hip_atomic_load(f, __ATOMIC_ACQUIRE, __HIP_MEMORY_SCOPE_AGENT) >= want) return;
  int g = 0;
  while (__hip_atomic_load(f, __ATOMIC_RELAXED, __HIP_MEMORY_SCOPE_AGENT) < want) {
    __builtin_amdgcn_s_sleep(2);
    if (++g > (1 << 27)) break;   // safety: avoid hard hang on protocol bug
  }
  int v = __hip_atomic_load(f, __ATOMIC_ACQUIRE, __HIP_MEMORY_SCOPE_AGENT);
  asm volatile("" :: "v"(v));     // keep the acquire load alive
}

struct Params {
  const float* obs; const float* fps; const float* dones; const float* states0;
  const float* b_fcx; const float* b_fcp; const float* b_fcm;
  const float* a_src; const float* a_dst;
  const float* b_lstm; const float* b_act;
  const float* W_cri; const float* b_cri;
  const int* acts; const int* nbr;
  float* out;
  float* h_buf;    // [2][N][NH]
  float* Wh_buf;   // [2][N][G3]
  float* dst_buf;  // [2][N]
  int* flag_h;     // [N*16] padded
  int* flag_w;     // [N*16]
  const __hip_bfloat16* lstmT; // [N][G4][512] = [ih row(384) | hh row(128)]
  const __hip_bfloat16* gatT;  // [G3][G3]
  const __hip_bfloat16* fcxT;  // [N][NFC][DX]
  const __hip_bfloat16* fcpT;  // [N][NFC][DP]
  const __hip_bfloat16* fcmT;  // [N][NFC][DM]
  const __hip_bfloat16* actT;  // [N][NA][NH]
};

// ---------------- prep kernels ----------------
__global__ void transpose_to_bf16(const float* __restrict__ src, __hip_bfloat16* __restrict__ dst,
                                  int A, int D, int G) {
  size_t total = (size_t)A * D * G;
  size_t stride = (size_t)gridDim.x * blockDim.x;
  for (size_t i = (size_t)blockIdx.x * blockDim.x + threadIdx.x; i < total; i += stride) {
    size_t dg = (size_t)D * G;
    size_t a = i / dg;
    size_t r = i - a * dg;
    size_t g = r / D, d = r - g * D;
    dst[i] = __float2bfloat16(src[a * dg + d * G + g]);
  }
}

__global__ void build_lstmT(const float* __restrict__ Wih, const float* __restrict__ Whh,
                            __hip_bfloat16* __restrict__ dst) {
  size_t total = (size_t)N_ * G4_ * 512;
  size_t stride = (size_t)gridDim.x * blockDim.x;
  for (size_t i = (size_t)blockIdx.x * blockDim.x + threadIdx.x; i < total; i += stride) {
    int d = (int)(i & 511);
    size_t r = i >> 9;
    int g = (int)(r & 511);
    int n = (int)(r >> 9);
    float v = (d < G3_) ? Wih[((size_t)n * G3_ + d) * G4_ + g]
                        : Whh[((size_t)n * NH_ + (d - G3_)) * G4_ + g];
    dst[i] = __float2bfloat16(v);
  }
}

__global__ void reset_flags(int* flag_h, int* flag_w) {
  int i = blockIdx.x * blockDim.x + threadIdx.x;
  if (i < N_ * 16) { flag_h[i] = 0; flag_w[i] = 0; }
}

// ---------------- main: 128 WGs x 1024 threads, ring p2p sync ----------------
__global__ void __launch_bounds__(1024, 4) policy_scan_p2p(Params p) {
  const int tid = threadIdx.x;
  const int bid = blockIdx.x;
  const int n   = ((bid & 7) << 4) | (bid >> 3);   // cluster ring neighbors per XCD
  const int nb0 = p.nbr[n * 2 + 0];
  const int nb1 = p.nbr[n * 2 + 1];

  __shared__ __align__(16) float sh_h[NH_];        // own raw h_t
  __shared__ __align__(16) float sh_c[NH_];        // own raw c_t
  __shared__ __align__(16) float sh_xin[DX_];
  __shared__ __align__(16) float sh_pin[DP_];
  __shared__ __align__(16) float sh_min[DM_];
  __shared__ __align__(16) float sh_feat[G3_];
  __shared__ __align__(16) float sh_Wh[G3_];
  __shared__ __align__(16) float sh_sx[512];       // [sgat(384) | masked own h(128)]
  __shared__ __align__(16) float sh_gates[G4_];
  __shared__ __align__(16) float partial[1024];
  __shared__ __align__(16) float red_s[G3_];
  __shared__ __align__(16) float red_d[G3_];
  __shared__ float sh_scal[2];                     // src_n, dst_n

  // ---- prologue: publish h version 0 ----
  if (tid < NH_) {
    float h0 = p.states0[n * (2 * NH_) + tid];
    float c0 = p.states0[n * (2 * NH_) + NH_ + tid];
    sh_h[tid] = h0; sh_c[tid] = c0;
    p.h_buf[n * NH_ + tid] = h0;                   // buffer 0 holds version 0
  }
  __syncthreads();
  if (tid == 0) {
    __threadfence();
    __hip_atomic_store(&p.flag_h[n * 16], 1, __ATOMIC_RELEASE, __HIP_MEMORY_SCOPE_AGENT);
  }

  for (int t = 0; t < T_; ++t) {
    const float keep  = 1.f - p.dones[(size_t)t * N_ + n];
    const float keep0 = 1.f - p.dones[(size_t)t * N_ + nb0];
    const float keep1 = 1.f - p.dones[(size_t)t * N_ + nb1];

    const float* hb_r  = p.h_buf  + (size_t)(t & 1) * N_ * NH_;
    float*       hb_w  = p.h_buf  + (size_t)((t + 1) & 1) * N_ * NH_;
    float*       whb   = p.Wh_buf + (size_t)(t & 1) * N_ * G3_;
    float*       dstb  = p.dst_buf + (size_t)(t & 1) * N_;

    // ---- A: stage h-independent inputs; tid0 waits for neighbor h ----
    if (tid < DX_) {
      int k = tid >> 6, d = tid & 63;
      int agent = (k == 0) ? n : ((k == 1) ? nb0 : nb1);
      sh_xin[tid] = p.obs[((size_t)t * N_ + agent) * NS_ + d];
    } else if (tid < DX_ + DP_) {
      int u = tid - DX_;
      int k = u >> 3, a = u & 7;
      int agent = (k == 0) ? nb0 : nb1;
      sh_pin[u] = p.fps[((size_t)t * N_ + agent) * NA_ + a];
    }
    if (tid == 0) {
      spin_ge(p.flag_h + nb0 * 16, t + 1);
      spin_ge(p.flag_h + nb1 * 16, t + 1);
    }
    __syncthreads();

    // ---- B: masked h (own -> sh_sx tail; neighbors -> sh_min) ----
    if (tid < NH_) {
      sh_sx[G3_ + tid] = sh_h[tid] * keep;
    } else if (tid >= 256 && tid < 512) {
      int v = tid - 256;
      int k = v >> 7, f = v & 127;
      int agent = (k == 0) ? nb0 : nb1;
      float kp  = (k == 0) ? keep0 : keep1;
      sh_min[v] = hb_r[agent * NH_ + f] * kp;
    }
    __syncthreads();

    // ---- C: stage-1 FCs, K-split ----
    {
      float pr = 0.f;
      if (tid < 512) {                 // fcm: 128 rows x 4-way K (64 each)
        int r = tid & 127, ks = tid >> 7;
        pr = dot_bf16T<8>(p.fcmT + ((size_t)n * NFC_ + r) * DM_ + ks * 64, sh_min + ks * 64);
      } else if (tid < 896) {          // fcx: 128 rows x 3-way K (64 each)
        int u = tid - 512;
        int r = u & 127, ks = u >> 7;
        pr = dot_bf16T<8>(p.fcxT + ((size_t)n * NFC_ + r) * DX_ + ks * 64, sh_xin + ks * 64);
      } else {                         // fcp: 128 rows, full K=16
        int r = tid - 896;
        pr = dot_bf16T<2>(p.fcpT + ((size_t)n * NFC_ + r) * DP_, sh_pin);
      }
      partial[tid] = pr;
    }
    __syncthreads();
    if (tid < 128) {                   // x
      float a = p.b_fcx[n * NFC_ + tid] + partial[512 + tid] + partial[640 + tid] + partial[768 + tid];
      sh_feat[tid] = fmaxf(a, 0.f);
    } else if (tid < 256) {            // p
      int r = tid - 128;
      float a = p.b_fcp[n * NFC_ + r] + partial[896 + r];
      sh_feat[128 + r] = fmaxf(a, 0.f);
    } else if (tid < 384) {            // m
      int r = tid - 256;
      float a = p.b_fcm[n * NFC_ + r] + partial[r] + partial[128 + r] + partial[256 + r] + partial[384 + r];
      sh_feat[256 + r] = fmaxf(a, 0.f);
    }
    __syncthreads();

    // ---- D: Wh = feat @ Wgat (384 rows x 2-way K) ----
    if (tid < 768) {
      int r = tid & 383, ks = tid >> 9;  // careful: 768 = 2*384 -> ks = tid/384
      ks = tid / 384; r = tid - ks * 384;
      partial[tid] = dot_bf16T<24>(p.gatT + (size_t)r * G3_ + ks * 192, sh_feat + ks * 192);
    }
    __syncthreads();
    if (tid < G3_) {
      float wh = partial[tid] + partial[384 + tid];
      sh_Wh[tid] = wh;
      whb[n * G3_ + tid] = wh;
      red_s[tid] = wh * p.a_src[tid];
      red_d[tid] = wh * p.a_dst[tid];
    }
    __syncthreads();
    if (tid < 64) {
      float s = red_s[tid] + red_s[tid + 64] + red_s[tid + 128]
              + red_s[tid + 192] + red_s[tid + 256] + red_s[tid + 320];
      for (int off = 32; off; off >>= 1) s += __shfl_down(s, off);
      if (tid == 0) sh_scal[0] = s;
    } else if (tid < 128) {
      int l = tid - 64;
      float s = red_d[l] + red_d[l + 64] + red_d[l + 128]
              + red_d[l + 192] + red_d[l + 256] + red_d[l + 320];
      for (int off = 32; off; off >>= 1) s += __shfl_down(s, off);
      if (l == 0) { sh_scal[1] = s; dstb[n] = s; }
    }
    __syncthreads();

    // ---- publish Wh/dst, then wait for neighbors' ----
    if (tid == 0) {
      __threadfence();
      __hip_atomic_store(&p.flag_w[n * 16], t + 1, __ATOMIC_RELEASE, __HIP_MEMORY_SCOPE_AGENT);
      spin_ge(p.flag_w + nb0 * 16, t + 1);
      spin_ge(p.flag_w + nb1 * 16, t + 1);
    }
    __syncthreads();

    // ---- E: attention + s_gat ----
    {
      float src_n = sh_scal[0];
      float e_l = src_n + dstb[nb0];
      float e_s = src_n + sh_scal[1];
      float e_r = src_n + dstb[nb1];
      e_l = (e_l >= 0.f) ? e_l : 0.2f * e_l;
      e_s = (e_s >= 0.f) ? e_s : 0.2f * e_s;
      e_r = (e_r >= 0.f) ? e_r : 0.2f * e_r;
      float mx = fmaxf(e_l, fmaxf(e_s, e_r));
      float wl = expf(e_l - mx), wsf = expf(e_s - mx), wr = expf(e_r - mx);
      float inv = 1.f / (wl + wsf + wr);
      wl *= inv; wsf *= inv; wr *= inv;
      if (tid < G3_) {
        float v = wsf * sh_Wh[tid]
                + wl  * whb[nb0 * G3_ + tid]
                + wr  * whb[nb1 * G3_ + tid];
        sh_sx[tid] = (v > 0.f) ? v : expm1f(v);   // elu
      }
    }
    __syncthreads();

    // ---- F: LSTM gates (512 rows x 2-way K over combined [sgat|hm]) ----
    {
      int r = tid & 511, kh = tid >> 9;
      partial[tid] = dot_bf16T<32>(p.lstmT + ((size_t)n * G4_ + r) * 512 + kh * 256,
                                   sh_sx + kh * 256);
    }
    __syncthreads();
    if (tid < G4_) {
      sh_gates[tid] = partial[tid] + partial[512 + tid] + p.b_lstm[n * G4_ + tid];
    }
    __syncthreads();

    // ---- G: state update + publish h ----
    if (tid < NH_) {
      float gi = sh_gates[tid];
      float gf = sh_gates[NH_ + tid];
      float gg = sh_gates[2 * NH_ + tid];
      float go = sh_gates[3 * NH_ + tid];
      float c_new = sigm(gf) * (sh_c[tid] * keep) + sigm(gi) * tanhf(gg);
      float h_new = sigm(go) * tanhf(c_new);
      sh_c[tid] = c_new;
      sh_h[tid] = h_new;
      hb_w[n * NH_ + tid] = h_new;
    }
    __syncthreads();
    if (tid == 0) {
      __threadfence();
      __hip_atomic_store(&p.flag_h[n * 16], t + 2, __ATOMIC_RELEASE, __HIP_MEMORY_SCOPE_AGENT);
    }

    // ---- H: heads (overlap with neighbors' progress; own data only) ----
    if (tid >= 128 && tid < 192) {
      int l = tid - 128, a = l >> 3, k = l & 7;
      const uint4* wv = reinterpret_cast<const uint4*>(p.actT + ((size_t)n * NA_ + a) * NH_);
      const float4* xv = reinterpret_cast<const float4*>(sh_h);
      float pp = 0.f;
      #pragma unroll
      for (int i = 0; i < 2; ++i) {
        uint4 u = wv[k * 2 + i];
        float4 x0 = xv[(k * 2 + i) * 2];
        float4 x1 = xv[(k * 2 + i) * 2 + 1];
        pp = fmaf(__uint_as_float(u.x << 16),         x0.x, pp);
        pp = fmaf(__uint_as_float(u.x & 0xffff0000u), x0.y, pp);
        pp = fmaf(__uint_as_float(u.y << 16),         x0.z, pp);
        pp = fmaf(__uint_as_float(u.y & 0xffff0000u), x0.w, pp);
        pp = fmaf(__uint_as_float(u.z << 16),         x1.x, pp);
        pp = fmaf(__uint_as_float(u.z & 0xffff0000u), x1.y, pp);
        pp = fmaf(__uint_as_float(u.w << 16),         x1.z, pp);
        pp = fmaf(__uint_as_float(u.w & 0xffff0000u), x1.w, pp);
      }
      pp += __shfl_down(pp, 4, 8);
      pp += __shfl_down(pp, 2, 8);
      pp += __shfl_down(pp, 1, 8);
      if (k == 0) p.out[((size_t)t * N_ + n) * 9 + a] = pp + p.b_act[n * NA_ + a];
    } else if (tid >= 192 && tid < 256) {
      int l = tid - 192;
      const float* wc = p.W_cri + (size_t)n * 144;
      float pp = sh_h[l] * wc[l] + sh_h[64 + l] * wc[64 + l];
      for (int off = 32; off; off >>= 1) pp += __shfl_down(pp, off);
      if (l == 0) {
        pp += p.b_cri[n];
        pp += wc[NH_ + p.acts[(size_t)t * N_ + nb0]];
        pp += wc[NH_ + NA_ + p.acts[(size_t)t * N_ + nb1]];
        p.out[((size_t)t * N_ + n) * 9 + 8] = pp;
      }
    }
    // no barrier needed: next-iter staging touches disjoint LDS, then syncs.
  }
}

// ---------------- fallback: fp32 streaming kernel (ws too small) ----------------
struct ParamsF {
  const float* obs; const float* fps; const float* dones; const float* states0;
  const float* W_fcx; const float* b_fcx;
  const float* W_fcp; const float* b_fcp;
  const float* W_fcm; const float* b_fcm;
  const float* W_gat; const float* a_src; const float* a_dst;
  const float* W_ih;  const float* W_hh;  const float* b_lstm;
  const float* W_act; const float* b_act;
  const float* W_cri; const float* b_cri;
  const int* acts; const int* nbr;
  float* out; float* h_buf; float* Wh_buf; float* dst_buf;
};

__global__ void __launch_bounds__(512) policy_scan_f32(ParamsF p) {
  cg::grid_group grid = cg::this_grid();
  const int tid = threadIdx.x;
  const int n   = blockIdx.x;
  const int nb0 = p.nbr[n * 2 + 0];
  const int nb1 = p.nbr[n * 2 + 1];
  __shared__ float sh_h[NH_], sh_c[NH_], sh_xin[DX_], sh_pin[DP_], sh_min[DM_];
  __shared__ float sh_feat[G3_], sh_Wh[G3_], sh_sgat[G3_], sh_gates[G4_], sh_src;
  if (tid < NH_) {
    float h0 = p.states0[n * (2 * NH_) + tid];
    float c0 = p.states0[n * (2 * NH_) + NH_ + tid];
    sh_h[tid] = h0; sh_c[tid] = c0; p.h_buf[n * NH_ + tid] = h0;
  }
  __threadfence();
  grid.sync();
  for (int t = 0; t < T_; ++t) {
    const float keep  = 1.f - p.dones[(size_t)t * N_ + n];
    const float keep0 = 1.f - p.dones[(size_t)t * N_ + nb0];
    const float keep1 = 1.f - p.dones[(size_t)t * N_ + nb1];
    if (tid < NH_) { sh_h[tid] *= keep; sh_c[tid] *= keep; }
    if (tid < DX_) {
      int k = tid >> 6, d = tid & 63;
      int agent = (k == 0) ? n : ((k == 1) ? nb0 : nb1);
      sh_xin[tid] = p.obs[((size_t)t * N_ + agent) * NS_ + d];
    }
    {
      int u = tid - DX_;
      if (u >= 0 && u < DP_) {
        int k = u >> 3, a = u & 7;
        sh_pin[u] = p.fps[((size_t)t * N_ + ((k == 0) ? nb0 : nb1)) * NA_ + a];
      }
      int v = tid - (DX_ + DP_);
      if (v >= 0 && v < DM_) {
        int k = v >> 7, f = v & 127;
        sh_min[v] = p.h_buf[((k == 0) ? nb0 : nb1) * NH_ + f] * ((k == 0) ? keep0 : keep1);
      }
    }
    __syncthreads();
    if (tid < NFC_) {
      const float* w = p.W_fcx + ((size_t)n * DX_) * NFC_ + tid;
      float acc = p.b_fcx[n * NFC_ + tid];
      #pragma unroll 4
      for (int d = 0; d < DX_; ++d) acc = fmaf(sh_xin[d], w[(size_t)d * NFC_], acc);
      sh_feat[tid] = fmaxf(acc, 0.f);
    } else if (tid < 2 * NFC_) {
      int f = tid - NFC_;
      const float* w = p.W_fcp + ((size_t)n * DP_) * NFC_ + f;
      float acc = p.b_fcp[n * NFC_ + f];
      #pragma unroll
      for (int d = 0; d < DP_; ++d) acc = fmaf(sh_pin[d], w[(size_t)d * NFC_], acc);
      sh_feat[NFC_ + f] = fmaxf(acc, 0.f);
    } else if (tid < 3 * NFC_) {
      int f = tid - 2 * NFC_;
      const float* w = p.W_fcm + ((size_t)n * DM_) * NFC_ + f;
      float acc = p.b_fcm[n * NFC_ + f];
      #pragma unroll 4
      for (int d = 0; d < DM_; ++d) acc = fmaf(sh_min[d], w[(size_t)d * NFC_], acc);
      sh_feat[2 * NFC_ + f] = fmaxf(acc, 0.f);
    }
    __syncthreads();
    if (tid < G3_) {
      const float* w = p.W_gat + tid;
      float acc = 0.f;
      #pragma unroll 4
      for (int d = 0; d < G3_; ++d) acc = fmaf(sh_feat[d], w[(size_t)d * G3_], acc);
      sh_Wh[tid] = acc;
      p.Wh_buf[n * G3_ + tid] = acc;
    }
    __syncthreads();
    if (tid < 64) {
      float s = 0.f;
      for (int g = tid; g < G3_; g += 64) s += sh_Wh[g] * p.a_src[g];
      for (int off = 32; off; off >>= 1) s += __shfl_down(s, off);
      if (tid == 0) sh_src = s;
    } else if (tid < 128) {
      int l = tid - 64;
      float s = 0.f;
      for (int g = l; g < G3_; g += 64) s += sh_Wh[g] * p.a_dst[g];
      for (int off = 32; off; off >>= 1) s += __shfl_down(s, off);
      if (l == 0) p.dst_buf[n] = s;
    }
    __threadfence();
    grid.sync();
    const float src_n = sh_src;
    float e_l = src_n + p.dst_buf[nb0];
    float e_s = src_n + p.dst_buf[n];
    float e_r = src_n + p.dst_buf[nb1];
    e_l = (e_l >= 0.f) ? e_l : 0.2f * e_l;
    e_s = (e_s >= 0.f) ? e_s : 0.2f * e_s;
    e_r = (e_r >= 0.f) ? e_r : 0.2f * e_r;
    float mx = fmaxf(e_l, fmaxf(e_s, e_r));
    float wl = expf(e_l - mx), wsf = expf(e_s - mx), wr = expf(e_r - mx);
    float inv = 1.f / (wl + wsf + wr);
    wl *= inv; wsf *= inv; wr *= inv;
    if (tid < G3_) {
      float v = wsf * sh_Wh[tid] + wl * p.Wh_buf[nb0 * G3_ + tid] + wr * p.Wh_buf[nb1 * G3_ + tid];
      sh_sgat[tid] = (v > 0.f) ? v : expm1f(v);
    }
    __syncthreads();
    {
      const int g = tid;
      const float* wih = p.W_ih + ((size_t)n * G3_) * G4_ + g;
      const float* whh = p.W_hh + ((size_t)n * NH_) * G4_ + g;
      float acc = p.b_lstm[n * G4_ + g];
      #pragma unroll 4
      for (int d = 0; d < G3_; ++d) acc = fmaf(sh_sgat[d], wih[(size_t)d * G4_], acc);
      #pragma unroll 4
      for (int d = 0; d < NH_; ++d) acc = fmaf(sh_h[d], whh[(size_t)d * G4_], acc);
      sh_gates[g] = acc;
    }
    __syncthreads();
    if (tid < NH_) {
      float gi = sh_gates[tid], gf = sh_gates[NH_ + tid];
      float gg = sh_gates[2 * NH_ + tid], go = sh_gates[3 * NH_ + tid];
      float c_new = sigm(gf) * sh_c[tid] + sigm(gi) * tanhf(gg);
      float h_new = sigm(go) * tanhf(c_new);
      sh_c[tid] = c_new; sh_h[tid] = h_new;
      p.h_buf[n * NH_ + tid] = h_new;
    }
    __syncthreads();
    if (tid < NA_) {
      const float* wa = p.W_act + ((size_t)n * NH_) * NA_ + tid;
      float acc = p.b_act[n * NA_ + tid];
      #pragma unroll 4
      for (int d = 0; d < NH_; ++d) acc = fmaf(sh_h[d], wa[(size_t)d * NA_], acc);
      p.out[((size_t)t * N_ + n) * 9 + tid] = acc;
    } else if (tid == NA_) {
      const float* wc = p.W_cri + (size_t)n * 144;
      float acc = p.b_cri[n];
      #pragma unroll 4
      for (int d = 0; d < NH_; ++d) acc = fmaf(sh_h[d], wc[d], acc);
      acc += wc[NH_ + p.acts[(size_t)t * N_ + nb0]];
      acc += wc[NH_ + NA_ + p.acts[(size_t)t * N_ + nb1]];
      p.out[((size_t)t * N_ + n) * 9 + 8] = acc;
    }
    __threadfence();
    grid.sync();
  }
}

extern "C" void kernel_launch(void* const* d_in, const int* in_sizes, int n_in,
                              void* d_out, int out_size, void* d_ws, size_t ws_size,
                              hipStream_t stream) {
  const float* obs    = (const float*)d_in[0];
  const float* fps    = (const float*)d_in[1];
  const float* dones  = (const float*)d_in[2];
  const float* states0= (const float*)d_in[3];
  const float* W_fcx  = (const float*)d_in[4];
  const float* b_fcx  = (const float*)d_in[5];
  const float* W_fcp  = (const float*)d_in[6];
  const float* b_fcp  = (const float*)d_in[7];
  const float* W_fcm  = (const float*)d_in[8];
  const float* b_fcm  = (const float*)d_in[9];
  const float* W_gat  = (const float*)d_in[10];
  const float* a_src  = (const float*)d_in[11];
  const float* a_dst  = (const float*)d_in[12];
  const float* W_ih   = (const float*)d_in[13];
  const float* W_hh   = (const float*)d_in[14];
  const float* b_lstm = (const float*)d_in[15];
  const float* W_act  = (const float*)d_in[16];
  const float* b_act  = (const float*)d_in[17];
  const float* W_cri  = (const float*)d_in[18];
  const float* b_cri  = (const float*)d_in[19];
  const int*   acts   = (const int*)d_in[20];
  const int*   nbr    = (const int*)d_in[21];

  char* ws = (char*)d_ws;
  size_t off = 0;
  float* h_buf   = (float*)(ws + off); off += (size_t)2 * N_ * NH_ * 4;
  float* Wh_buf  = (float*)(ws + off); off += (size_t)2 * N_ * G3_ * 4;
  float* dst_buf = (float*)(ws + off); off += 1024;
  int*   flag_h  = (int*)(ws + off);   off += (size_t)N_ * 16 * 4;
  int*   flag_w  = (int*)(ws + off);   off += (size_t)N_ * 16 * 4;
  __hip_bfloat16* lstmT = (__hip_bfloat16*)(ws + off); off += (size_t)N_ * G4_ * 512 * 2;
  __hip_bfloat16* gatT  = (__hip_bfloat16*)(ws + off); off += (size_t)G3_ * G3_ * 2;
  __hip_bfloat16* fcxT  = (__hip_bfloat16*)(ws + off); off += (size_t)N_ * NFC_ * DX_ * 2;
  __hip_bfloat16* fcpT  = (__hip_bfloat16*)(ws + off); off += (size_t)N_ * NFC_ * DP_ * 2;
  __hip_bfloat16* fcmT  = (__hip_bfloat16*)(ws + off); off += (size_t)N_ * NFC_ * DM_ * 2;
  __hip_bfloat16* actT  = (__hip_bfloat16*)(ws + off); off += (size_t)N_ * NA_ * NH_ * 2;

  if (ws_size < off) {
    ParamsF p;
    p.obs = obs; p.fps = fps; p.dones = dones; p.states0 = states0;
    p.W_fcx = W_fcx; p.b_fcx = b_fcx; p.W_fcp = W_fcp; p.b_fcp = b_fcp;
    p.W_fcm = W_fcm; p.b_fcm = b_fcm; p.W_gat = W_gat; p.a_src = a_src; p.a_dst = a_dst;
    p.W_ih = W_ih; p.W_hh = W_hh; p.b_lstm = b_lstm;
    p.W_act = W_act; p.b_act = b_act; p.W_cri = W_cri; p.b_cri = b_cri;
    p.acts = acts; p.nbr = nbr; p.out = (float*)d_out;
    p.h_buf = h_buf; p.Wh_buf = Wh_buf; p.dst_buf = dst_buf;
    void* args[] = { &p };
    hipLaunchCooperativeKernel((const void*)policy_scan_f32, dim3(N_), dim3(512), args, 0, stream);
    return;
  }

  // prep: flags reset + weight transposes (bf16 [out][in])
  reset_flags<<<dim3(2), dim3(1024), 0, stream>>>(flag_h, flag_w);
  {
    dim3 blk(256);
    build_lstmT<<<dim3(4096), blk, 0, stream>>>(W_ih, W_hh, lstmT);
    transpose_to_bf16<<<dim3(256),  blk, 0, stream>>>(W_gat, gatT, 1,  G3_, G3_);
    transpose_to_bf16<<<dim3(1024), blk, 0, stream>>>(W_fcx, fcxT, N_, DX_, NFC_);
    transpose_to_bf16<<<dim3(256),  blk, 0, stream>>>(W_fcp, fcpT, N_, DP_, NFC_);
    transpose_to_bf16<<<dim3(1024), blk, 0, stream>>>(W_fcm, fcmT, N_, DM_, NFC_);
    transpose_to_bf16<<<dim3(128),  blk, 0, stream>>>(W_act, actT, N_, NH_, NA_);
  }

  Params p;
  p.obs = obs; p.fps = fps; p.dones = dones; p.states0 = states0;
  p.b_fcx = b_fcx; p.b_fcp = b_fcp; p.b_fcm = b_fcm;
  p.a_src = a_src; p.a_dst = a_dst;
  p.b_lstm = b_lstm; p.b_act = b_act;
  p.W_cri = W_cri; p.b_cri = b_cri;
  p.acts = acts; p.nbr = nbr;
  p.out = (float*)d_out;
  p.h_buf = h_buf; p.Wh_buf = Wh_buf; p.dst_buf = dst_buf;
  p.flag_h = flag_h; p.flag_w = flag_w;
  p.lstmT = lstmT; p.gatT = gatT;
  p.fcxT = fcxT; p.fcpT = fcpT; p.fcmT = fcmT; p.actT = actT;

  void* args[] = { &p };
  hipLaunchCooperativeKernel((const void*)policy_scan_p2p, dim3(N_), dim3(1024), args, 0, stream);
}